// Round 25
// baseline (199.514 us; speedup 1.0000x reference)
//
#include <hip/hip_runtime.h>

typedef unsigned short u16;
typedef short s16x8 __attribute__((ext_vector_type(8)));
typedef float f32x4 __attribute__((ext_vector_type(4)));
typedef float f32x16 __attribute__((ext_vector_type(16)));

__device__ __forceinline__ u16 f2bf(float f) {
  union { float f; unsigned u; } x; x.f = f;
  unsigned r = (x.u + 0x7fffu + ((x.u >> 16) & 1u)) >> 16;
  return (u16)r;
}
__device__ __forceinline__ unsigned bfbits_t(float f) {   // truncating, as u32 low bits
  union { float f; unsigned u; } x; x.f = f;
  return x.u >> 16;
}
__device__ __forceinline__ float bf2f(u16 u) {
  union { unsigned u; float f; } x; x.u = ((unsigned)u) << 16;
  return x.f;
}

__device__ __forceinline__ void load_lds16(const u16* g, void* lds) {
  __builtin_amdgcn_global_load_lds(
      (const __attribute__((address_space(1))) unsigned int*)g,
      (__attribute__((address_space(3))) unsigned int*)lds, 16, 0, 0);
}

// ---------------- fused prep kernel ----------------
__global__ __launch_bounds__(256) void prep_kernel(
    const float* __restrict__ x,
    const float* __restrict__ wq, const float* __restrict__ wk,
    const float* __restrict__ wv,
    const float* __restrict__ bq, const float* __restrict__ bk,
    const float* __restrict__ bv,
    const float* __restrict__ wo,
    u16* __restrict__ xb, u16* __restrict__ wqkv,
    float* __restrict__ bqkv, u16* __restrict__ wob,
    float* __restrict__ cosb, float* __restrict__ sinb) {
  const int R0 = 2097152;            // x: 4096*2048/4
  const int R1 = R0 + 1572864;       // wqkv: 3072*2048/4
  const int R2 = R1 + 1048576;       // wo: 2048*2048/4
  const int R3 = R2 + 768;           // bias: 3072/4
  const int R4 = R3 + 131072;        // rope table: 2048*64
  for (int id = blockIdx.x * 256 + threadIdx.x; id < R4; id += gridDim.x * 256) {
    if (id < R0) {
      float4 v = ((const float4*)x)[id];
      u16* d = xb + (size_t)id * 4;
      d[0] = f2bf(v.x); d[1] = f2bf(v.y); d[2] = f2bf(v.z); d[3] = f2bf(v.w);
    } else if (id < R1) {
      int g = id - R0;
      int row = g >> 9, c4 = (g & 511) * 4;
      const float* src; int srow;
      if (row < 2048)      { src = wq; srow = row; }
      else if (row < 2560) { src = wk; srow = row - 2048; }
      else                 { src = wv; srow = row - 2560; }
      float4 v = *(const float4*)&src[(size_t)srow * 2048 + c4];
      u16* d = wqkv + (size_t)row * 2048 + c4;
      d[0] = f2bf(v.x); d[1] = f2bf(v.y); d[2] = f2bf(v.z); d[3] = f2bf(v.w);
    } else if (id < R2) {
      int g = id - R1;
      float4 v = ((const float4*)wo)[g];
      u16* d = wob + (size_t)g * 4;
      d[0] = f2bf(v.x); d[1] = f2bf(v.y); d[2] = f2bf(v.z); d[3] = f2bf(v.w);
    } else if (id < R3) {
      int g4 = (id - R2) * 4;        // boundaries 2048/2560 are 4-aligned
      float4 v;
      if (g4 < 2048)      v = *(const float4*)&bq[g4];
      else if (g4 < 2560) v = *(const float4*)&bk[g4 - 2048];
      else                v = *(const float4*)&bv[g4 - 2560];
      *(float4*)&bqkv[g4] = v;
    } else {
      int g = id - R3;
      int s = g >> 6, i = g & 63;
      float freq = powf(10000.0f, -(float)i / 64.0f);
      float ang = (float)s * freq;
      cosb[g] = cosf(ang);
      sinb[g] = sinf(ang);
    }
  }
}

// in-place RoPE on Qb (32*2048 rows) and Kbuf (8*2048 rows), fused
__global__ __launch_bounds__(256) void rope_all_kernel(u16* __restrict__ Qb,
                                                       u16* __restrict__ Kbuf,
                                                       const float* __restrict__ cosb,
                                                       const float* __restrict__ sinb) {
  const int total = (32 + 8) * 2048 * 64;   // 5,242,880
  for (int id = blockIdx.x * 256 + threadIdx.x; id < total; id += gridDim.x * 256) {
    int i = id & 63;
    int rs = id >> 6;
    int s = rs & 2047;
    u16* p;
    size_t base;
    if (rs < 65536) { p = Qb;   base = (size_t)rs * 128; }
    else            { p = Kbuf; base = (size_t)(rs - 65536) * 128; }
    float x1 = bf2f(p[base + i]);
    float x2 = bf2f(p[base + i + 64]);
    float c = cosb[s * 64 + i], sn = sinb[s * 64 + i];
    p[base + i]      = f2bf(x1 * c - x2 * sn);
    p[base + i + 64] = f2bf(x2 * c + x1 * sn);
  }
}

// ---------------- bf16 MFMA GEMM v3b: 8-wave 128x128, BK=64, direct-Vt write ------
// Identical to the verified r16/r22 kernel except the mode-0 V branch stores
// directly into the TRANSPOSED Vt layout [kvh][d][s] — eliminates the separate
// transpose_v kernel and its 33 MB round-trip. Same logical bytes; each block's
// epilogue fully dirties every touched 64B sector (s spans the block's 128 rows),
// so L2 write-combining keeps HBM WRITE_SIZE unchanged.
__global__ __launch_bounds__(512) void gemm_bt_kernel(
    const u16* __restrict__ A, const u16* __restrict__ Bw,
    const float* __restrict__ bias,
    float* __restrict__ C, int ldc,
    u16* __restrict__ Qp, u16* __restrict__ Kp, u16* __restrict__ Vtp,
    int M, int N, int K, int mode) {
  __shared__ u16 sA[128 * 64];   // 16 KB
  __shared__ u16 sB[128 * 64];   // 16 KB
  const int t = threadIdx.x;     // 0..511
  const int w = t >> 6, l = t & 63;
  const int lg = l >> 4, lr = l & 15;
  const int wm = (w >> 2) * 64, wn = (w & 3) * 32;
  const int m0 = blockIdx.y * 128, n0 = blockIdx.x * 128;

  f32x4 acc[4][2];
#pragma unroll
  for (int i = 0; i < 4; ++i)
#pragma unroll
    for (int j = 0; j < 2; ++j)
#pragma unroll
      for (int r = 0; r < 4; ++r) acc[i][j][r] = 0.0f;

  for (int k0 = 0; k0 < K; k0 += 64) {
#pragma unroll
    for (int i = 0; i < 2; ++i) {
      int c = i * 512 + t;
      int row = c >> 3, cc = (c & 7) ^ (row & 7);
      load_lds16(A + (size_t)(m0 + row) * K + k0 + cc * 8,
                 (char*)sA + i * 8192 + w * 1024);
      load_lds16(Bw + (size_t)(n0 + row) * K + k0 + cc * 8,
                 (char*)sB + i * 8192 + w * 1024);
    }
    __syncthreads();
#pragma unroll
    for (int kc = 0; kc < 2; ++kc) {
      const int rch = (((kc * 4 + lg) ^ (lr & 7)) * 8);
      s16x8 af[4], bf[2];
#pragma unroll
      for (int m = 0; m < 4; ++m)
        af[m] = *(const s16x8*)&sA[(wm + m * 16 + lr) * 64 + rch];
#pragma unroll
      for (int n = 0; n < 2; ++n)
        bf[n] = *(const s16x8*)&sB[(wn + n * 16 + lr) * 64 + rch];
#pragma unroll
      for (int m = 0; m < 4; ++m)
#pragma unroll
        for (int n = 0; n < 2; ++n)
          acc[m][n] = __builtin_amdgcn_mfma_f32_16x16x32_bf16(af[m], bf[n], acc[m][n], 0, 0, 0);
    }
    __syncthreads();
  }

#pragma unroll
  for (int m = 0; m < 4; ++m) {
#pragma unroll
    for (int n = 0; n < 2; ++n) {
#pragma unroll
      for (int r = 0; r < 4; ++r) {
        int row = m0 + wm + m * 16 + (lg << 2) + r;
        int col = n0 + wn + n * 16 + lr;
        float val = acc[m][n][r];
        if (mode == 0) {
          val += bias[col];
          int b = row >> 11, s = row & 2047;
          u16 bvv = f2bf(val);
          if (col < 2048) {
            int h = col >> 7, d = col & 127;
            Qp[(((size_t)(b * 16 + h)) * 2048 + s) * 128 + d] = bvv;
          } else if (col < 2560) {
            int cc = col - 2048; int kh = cc >> 7, d = cc & 127;
            Kp[(((size_t)(b * 4 + kh)) * 2048 + s) * 128 + d] = bvv;
          } else {
            int cc = col - 2560; int kh = cc >> 7, d = cc & 127;
            Vtp[((size_t)(b * 4 + kh) * 128 + d) * 2048 + s] = bvv;   // transposed
          }
        } else {
          C[(size_t)row * ldc + col] = val;
        }
      }
    }
  }
}

// ---------------- flash v14: KVB=128, 16-chunk 2-way-free swizzle (verified) -------
__device__ const int PH_QC[16] = {7,-1, 7,0, 6,-1, 6,1, 5,-1, 5,2, 4,-1, 4,3};
__device__ const int PH_J0[16] = {0,0, 9,0, 0,0, 9,0, 0,0, 9,0, 0,0, 9,0};
__device__ const int PH_NT[16] = {9,0, 7,2, 9,0, 5,4, 9,0, 3,6, 9,0, 1,8};
__device__ const int PH_MD[16] = {1,0, 2,0, 1,0, 2,0, 1,0, 2,0, 1,0, 2,0};

__global__ __launch_bounds__(512) void flash_mfma_kernel(const u16* __restrict__ Q,
                                                         const u16* __restrict__ Kb,
                                                         const u16* __restrict__ Vtb,
                                                         u16* __restrict__ O,
                                                         u16* __restrict__ po,
                                                         float* __restrict__ pml) {
  const int S = 2048;
  __shared__ u16 sK[128 * 128];      // [j][d], chunk XOR (j&15), single buffer
  __shared__ u16 sVt[2 * 128 * 128]; // [buf][d][j], chunk XOR (d&15)

  const int t = threadIdx.x, w = t >> 6, l = t & 63;
  const int l31 = l & 31, hi = l >> 5;
  const int bh = blockIdx.x, b = bh >> 4, h = bh & 15, kvh = h >> 2;
  const int slot = blockIdx.y;

  const u16* kbase = Kb + ((size_t)(b * 4 + kvh)) * S * 128;
  const u16* vtbase = Vtb + ((size_t)(b * 4 + kvh)) * 128 * S;

  const float C2 = 0.12753785f;   // (1/sqrt(128)) * log2(e)

  auto stageK = [&](int kt) {
#pragma unroll
    for (int i = 0; i < 4; ++i) {
      int c = i * 512 + t;
      int j = c >> 4, cc = (c & 15) ^ (j & 15);
      load_lds16(kbase + ((size_t)(kt * 128 + j) * 128 + cc * 8),
                 (char*)sK + (i * 8192 + w * 1024));
    }
  };
  auto stageV = [&](int kt, int buf) {
#pragma unroll
    for (int i = 0; i < 4; ++i) {
      int c = i * 512 + t;
      int d = c >> 4, cc = (c & 15) ^ (d & 15);
      load_lds16(vtbase + ((size_t)d * S + kt * 128 + cc * 8),
                 (char*)sVt + buf * 32768 + (i * 8192 + w * 1024));
    }
  };

#pragma unroll 1
  for (int ph = 0; ph < 2; ++ph) {
    const int qc = PH_QC[slot * 2 + ph];
    const int ntc = PH_NT[slot * 2 + ph];
    if (ntc == 0) break;
    const int j0 = PH_J0[slot * 2 + ph];
    const int md = PH_MD[slot * 2 + ph];
    const int qw = qc * 256 + w * 32;
    const int q_glob = qw + l31;

    // Q (B-operand) in regs: qb[ks][e] = Q[qw + l31][ks*16 + hi*8 + e]
    const u16* qbase = Q + ((size_t)bh * S + qw) * 128;
    s16x8 qb[8];
#pragma unroll
    for (int ks = 0; ks < 8; ++ks)
      qb[ks] = *(const s16x8*)&qbase[(size_t)l31 * 128 + ks * 16 + hi * 8];

    f32x16 o0, o1, o2, o3;
#pragma unroll
    for (int r = 0; r < 16; ++r) { o0[r] = 0.f; o1[r] = 0.f; o2[r] = 0.f; o3[r] = 0.f; }
    float mrun = -3e38f, lsum = 0.0f;

    stageV(j0, 0);
    stageK(j0);
    __syncthreads();   // drain -> K[j0], V[j0] ready

    int cur = 0;
    for (int kt2 = 0; kt2 < ntc; ++kt2) {
      const int kt = j0 + kt2;
      const bool act = (kt * 128 <= qw + 31);
      const bool more = (kt2 + 1 < ntc);

      if (more) stageV(kt + 1, cur ^ 1);   // V[cur^1] free since PV(kt-1)

      f32x16 sc0, sc1, sc2, sc3;
      if (act) {
        // ---- QK^T swapped: sc = mfma32(K, Q), 32 MFMA over 4 j-blocks ----
#pragma unroll
        for (int r = 0; r < 16; ++r) { sc0[r] = 0.f; sc1[r] = 0.f; sc2[r] = 0.f; sc3[r] = 0.f; }
        const int chkb = (l31 & 15);
        __builtin_amdgcn_s_setprio(1);
#pragma unroll
        for (int ks = 0; ks < 8; ++ks) {
          int chk = ((2 * ks + hi) ^ chkb) * 8;
          s16x8 kf0 = *(const s16x8*)&sK[(l31) * 128 + chk];
          s16x8 kf1 = *(const s16x8*)&sK[(32 + l31) * 128 + chk];
          s16x8 kf2 = *(const s16x8*)&sK[(64 + l31) * 128 + chk];
          s16x8 kf3 = *(const s16x8*)&sK[(96 + l31) * 128 + chk];
          sc0 = __builtin_amdgcn_mfma_f32_32x32x16_bf16(kf0, qb[ks], sc0, 0, 0, 0);
          sc1 = __builtin_amdgcn_mfma_f32_32x32x16_bf16(kf1, qb[ks], sc1, 0, 0, 0);
          sc2 = __builtin_amdgcn_mfma_f32_32x32x16_bf16(kf2, qb[ks], sc2, 0, 0, 0);
          sc3 = __builtin_amdgcn_mfma_f32_32x32x16_bf16(kf3, qb[ks], sc3, 0, 0, 0);
        }
        __builtin_amdgcn_s_setprio(0);
      }

      __syncthreads();   // barrier A: QK reads of sK done (drains V[kt+1] too)

      if (more) stageK(kt + 1);

      if (act) {
        const u16* sVc = &sVt[cur * 16384];

        // ---- causal mask (diagonal tiles only) ----
        if (kt * 128 + 127 > qw) {
          const int j0m = kt * 128;
#pragma unroll
          for (int r = 0; r < 16; ++r) {
            int jr = j0m + (r & 3) + 8 * (r >> 2) + 4 * hi;
            sc0[r] = (jr <= q_glob) ? sc0[r] : -3e38f;
            sc1[r] = (jr + 32 <= q_glob) ? sc1[r] : -3e38f;
            sc2[r] = (jr + 64 <= q_glob) ? sc2[r] : -3e38f;
            sc3[r] = (jr + 96 <= q_glob) ? sc3[r] : -3e38f;
          }
        }

        // ---- online softmax over full tile (defer-max THR=8) ----
        float tm[16];
#pragma unroll
        for (int r = 0; r < 16; ++r)
          tm[r] = fmaxf(fmaxf(sc0[r], sc1[r]), fmaxf(sc2[r], sc3[r]));
#pragma unroll
        for (int s2 = 8; s2 >= 1; s2 >>= 1)
#pragma unroll
          for (int r = 0; r < s2; ++r) tm[r] = fmaxf(tm[r], tm[r + s2]);
        float mt = fmaxf(tm[0], __shfl_xor(tm[0], 32));
        float mt2 = mt * C2;
        bool resc = (mt2 > mrun + 8.0f);
        if (resc) {
          float Mn = mt2;
          float corr = exp2f(mrun - Mn);
          lsum *= corr;
#pragma unroll
          for (int r = 0; r < 16; ++r) {
            o0[r] *= corr; o1[r] *= corr; o2[r] *= corr; o3[r] *= corr;
          }
          mrun = Mn;
        }
        const float Mn = mrun;
        float lacc = 0.0f;

        // ---- half 0: P from sc0/sc1 (j 0..63), PV with V chunks 0..7 ----
        {
          unsigned pk[16];
#pragma unroll
          for (int m = 0; m < 8; ++m) {
            float pa_ = exp2f(__builtin_fmaf(sc0[2 * m], C2, -Mn));
            float pb_ = exp2f(__builtin_fmaf(sc0[2 * m + 1], C2, -Mn));
            lacc += pa_ + pb_;
            pk[m] = (bfbits_t(pb_) << 16) | bfbits_t(pa_);
          }
#pragma unroll
          for (int m = 0; m < 8; ++m) {
            float pa_ = exp2f(__builtin_fmaf(sc1[2 * m], C2, -Mn));
            float pb_ = exp2f(__builtin_fmaf(sc1[2 * m + 1], C2, -Mn));
            lacc += pa_ + pb_;
            pk[8 + m] = (bfbits_t(pb_) << 16) | bfbits_t(pa_);
          }
          unsigned pkx[16];
#pragma unroll
          for (int i = 0; i < 16; ++i) pkx[i] = __shfl_xor(pk[i], 32);
          __builtin_amdgcn_s_setprio(1);
#pragma unroll
          for (int ks = 0; ks < 4; ++ks) {
            const int base = (ks >> 1) * 8 + 4 * (ks & 1);
            unsigned pw[4];
            pw[0] = hi ? pkx[base + 2] : pk[base + 0];
            pw[1] = hi ? pkx[base + 3] : pk[base + 1];
            pw[2] = hi ? pk[base + 2] : pkx[base + 0];
            pw[3] = hi ? pk[base + 3] : pkx[base + 1];
            s16x8 pa = *(const s16x8*)pw;
#pragma unroll
            for (int dt = 0; dt < 4; ++dt) {
              int d = dt * 32 + l31;
              s16x8 vt = *(const s16x8*)&sVc[d * 128 + (((2 * ks + hi) ^ (d & 15)) * 8)];
              if (dt == 0) o0 = __builtin_amdgcn_mfma_f32_32x32x16_bf16(vt, pa, o0, 0, 0, 0);
              if (dt == 1) o1 = __builtin_amdgcn_mfma_f32_32x32x16_bf16(vt, pa, o1, 0, 0, 0);
              if (dt == 2) o2 = __builtin_amdgcn_mfma_f32_32x32x16_bf16(vt, pa, o2, 0, 0, 0);
              if (dt == 3) o3 = __builtin_amdgcn_mfma_f32_32x32x16_bf16(vt, pa, o3, 0, 0, 0);
            }
          }
          __builtin_amdgcn_s_setprio(0);
        }

        // ---- half 1: P from sc2/sc3 (j 64..127), PV with V chunks 8..15 ----
        {
          unsigned pk[16];
#pragma unroll
          for (int m = 0; m < 8; ++m) {
            float pa_ = exp2f(__builtin_fmaf(sc2[2 * m], C2, -Mn));
            float pb_ = exp2f(__builtin_fmaf(sc2[2 * m + 1], C2, -Mn));
            lacc += pa_ + pb_;
            pk[m] = (bfbits_t(pb_) << 16) | bfbits_t(pa_);
          }
#pragma unroll
          for (int m = 0; m < 8; ++m) {
            float pa_ = exp2f(__builtin_fmaf(sc3[2 * m], C2, -Mn));
            float pb_ = exp2f(__builtin_fmaf(sc3[2 * m + 1], C2, -Mn));
            lacc += pa_ + pb_;
            pk[8 + m] = (bfbits_t(pb_) << 16) | bfbits_t(pa_);
          }
          unsigned pkx[16];
#pragma unroll
          for (int i = 0; i < 16; ++i) pkx[i] = __shfl_xor(pk[i], 32);
          __builtin_amdgcn_s_setprio(1);
#pragma unroll
          for (int ks = 0; ks < 4; ++ks) {
            const int base = (ks >> 1) * 8 + 4 * (ks & 1);
            unsigned pw[4];
            pw[0] = hi ? pkx[base + 2] : pk[base + 0];
            pw[1] = hi ? pkx[base + 3] : pk[base + 1];
            pw[2] = hi ? pk[base + 2] : pkx[base + 0];
            pw[3] = hi ? pk[base + 3] : pkx[base + 1];
            s16x8 pa = *(const s16x8*)pw;
#pragma unroll
            for (int dt = 0; dt < 4; ++dt) {
              int d = dt * 32 + l31;
              s16x8 vt = *(const s16x8*)&sVc[d * 128 + (((8 + 2 * ks + hi) ^ (d & 15)) * 8)];
              if (dt == 0) o0 = __builtin_amdgcn_mfma_f32_32x32x16_bf16(vt, pa, o0, 0, 0, 0);
              if (dt == 1) o1 = __builtin_amdgcn_mfma_f32_32x32x16_bf16(vt, pa, o1, 0, 0, 0);
              if (dt == 2) o2 = __builtin_amdgcn_mfma_f32_32x32x16_bf16(vt, pa, o2, 0, 0, 0);
              if (dt == 3) o3 = __builtin_amdgcn_mfma_f32_32x32x16_bf16(vt, pa, o3, 0, 0, 0);
            }
          }
          __builtin_amdgcn_s_setprio(0);
        }
        lsum += lacc;
      }

      __syncthreads();   // barrier B: drains K[kt+1]; protects sK reuse
      cur ^= 1;
    }

    // ---- epilogue: denominator reduce, normalize, store (full or partial) ----
    float ls = lsum + __shfl_xor(lsum, 32);
    float inv = (ls > 0.0f) ? 1.0f / ls : 0.0f;
    if (md == 0) {
      size_t obase = ((size_t)b * S + q_glob) * 2048 + h * 128;
#pragma unroll
      for (int dt = 0; dt < 4; ++dt) {
        const f32x16& ov = (dt == 0) ? o0 : (dt == 1) ? o1 : (dt == 2) ? o2 : o3;
#pragma unroll
        for (int g = 0; g < 4; ++g) {
          int d0 = dt * 32 + 8 * g + 4 * hi;
          unsigned u0 = (unsigned)f2bf(ov[4 * g] * inv) | ((unsigned)f2bf(ov[4 * g + 1] * inv) << 16);
          unsigned u1 = (unsigned)f2bf(ov[4 * g + 2] * inv) | ((unsigned)f2bf(ov[4 * g + 3] * inv) << 16);
          uint2 u; u.x = u0; u.y = u1;
          *(uint2*)&O[obase + d0] = u;
        }
      }
    } else {
      const int pid = ((bh << 2) + (qc - 4)) * 2 + (md - 1);
      const int qrow = w * 32 + l31;
      size_t pbase = (size_t)pid * 32768 + (size_t)qrow * 128;
#pragma unroll
      for (int dt = 0; dt < 4; ++dt) {
        const f32x16& ov = (dt == 0) ? o0 : (dt == 1) ? o1 : (dt == 2) ? o2 : o3;
#pragma unroll
        for (int g = 0; g < 4; ++g) {
          int d0 = dt * 32 + 8 * g + 4 * hi;
          unsigned u0 = (unsigned)f2bf(ov[4 * g] * inv) | ((unsigned)f2bf(ov[4 * g + 1] * inv) << 16);
          unsigned u1 = (unsigned)f2bf(ov[4 * g + 2] * inv) | ((unsigned)f2bf(ov[4 * g + 3] * inv) << 16);
          uint2 u; u.x = u0; u.y = u1;
          *(uint2*)&po[pbase + d0] = u;
        }
      }
      if (hi == 0) {
        pml[pid * 512 + qrow * 2]     = mrun;
        pml[pid * 512 + qrow * 2 + 1] = ls;
      }
    }
    if (ph == 0 && PH_NT[slot * 2 + 1] != 0) __syncthreads();
  }
}

// merge the two halves of each split q-tile: O = w0*o0 + w1*o1, wi = li*2^(mi-M).
__global__ __launch_bounds__(256) void flash_merge_kernel(const u16* __restrict__ po,
                                                          const float* __restrict__ pml,
                                                          u16* __restrict__ att) {
  const int t = threadIdx.x;
  const int tl = blockIdx.x >> 4;            // 0..127
  const int row = (blockIdx.x & 15) * 16 + (t >> 4);
  const int d8 = (t & 15) * 8;
  const int hh2 = tl >> 2, qc = (tl & 3) + 4;
  const int pid0 = tl * 2, pid1 = pid0 + 1;
  float m0 = pml[pid0 * 512 + row * 2], l0 = pml[pid0 * 512 + row * 2 + 1];
  float m1 = pml[pid1 * 512 + row * 2], l1 = pml[pid1 * 512 + row * 2 + 1];
  float M = fmaxf(m0, m1);
  float w0 = l0 * exp2f(m0 - M), w1 = l1 * exp2f(m1 - M);
  float inv = 1.0f / (w0 + w1);
  w0 *= inv; w1 *= inv;
  s16x8 a = *(const s16x8*)&po[(size_t)pid0 * 32768 + row * 128 + d8];
  s16x8 c = *(const s16x8*)&po[(size_t)pid1 * 32768 + row * 128 + d8];
  int b = hh2 >> 4, hh = hh2 & 15;
  size_t base = ((size_t)b * 2048 + qc * 256 + row) * 2048 + hh * 128 + d8;
  u16 outv[8];
#pragma unroll
  for (int e = 0; e < 8; ++e)
    outv[e] = f2bf(w0 * bf2f((u16)a[e]) + w1 * bf2f((u16)c[e]));
  *(s16x8*)&att[base] = *(const s16x8*)outv;
}

// ---------------- launch ----------------

extern "C" void kernel_launch(void* const* d_in, const int* in_sizes, int n_in,
                              void* d_out, int out_size, void* d_ws, size_t ws_size,
                              hipStream_t stream) {
  const float* x  = (const float*)d_in[0];
  const float* wq = (const float*)d_in[1];
  const float* bq = (const float*)d_in[2];
  const float* wk = (const float*)d_in[3];
  const float* bk = (const float*)d_in[4];
  const float* wv = (const float*)d_in[5];
  const float* bv = (const float*)d_in[6];
  const float* wo = (const float*)d_in[7];
  float* out = (float*)d_out;

  char* ws = (char*)d_ws;
  u16* xb    = (u16*)ws;    ws += (size_t)4096 * 2048 * 2;
  u16* wqkv  = (u16*)ws;    ws += (size_t)3072 * 2048 * 2;
  float* bqkv = (float*)ws; ws += (size_t)3072 * 4;
  u16* wob   = (u16*)ws;    ws += (size_t)2048 * 2048 * 2;
  u16* Qb    = (u16*)ws;    ws += (size_t)32 * 2048 * 128 * 2;
  u16* Kbuf  = (u16*)ws;    ws += (size_t)8 * 2048 * 128 * 2;
  u16* Vbuf  = (u16*)ws;    ws += (size_t)8 * 2048 * 128 * 2;  // scratch: pml alias only
  u16* Vt    = (u16*)ws;    ws += (size_t)8 * 128 * 2048 * 2;
  float* cosb = (float*)ws; ws += (size_t)2048 * 64 * 4;
  float* sinb = (float*)ws; ws += (size_t)2048 * 64 * 4;
  u16* att   = (u16*)ws;    ws += (size_t)4096 * 2048 * 2;

  // partial buffers ALIAS dead regions (stream-ordered, safe):
  u16* po = xb;              // 256 partials x 64 KB = 16.78 MB = xb exactly; xb dead after qkv GEMM
  float* pml = (float*)Vbuf; // 256 x 512 floats = 524 KB; Vbuf is pure scratch now

  prep_kernel<<<2048, 256, 0, stream>>>(x, wq, wk, wv, bq, bk, bv, wo,
                                        xb, wqkv, bqkv, wob, cosb, sinb);

  gemm_bt_kernel<<<dim3(24, 32), 512, 0, stream>>>(xb, wqkv, bqkv, nullptr, 0,
                                                   Qb, Kbuf, Vt, 4096, 3072, 2048, 0);
  rope_all_kernel<<<2048, 256, 0, stream>>>(Qb, Kbuf, cosb, sinb);

  flash_mfma_kernel<<<dim3(32, 8), 512, 0, stream>>>(Qb, Kbuf, Vt, att, po, pml);
  flash_merge_kernel<<<2048, 256, 0, stream>>>(po, pml, att);

  gemm_bt_kernel<<<dim3(16, 32), 512, 0, stream>>>(att, wob, nullptr, out, 2048,
                                                   nullptr, nullptr, nullptr, 4096, 2048, 2048, 1);
}

// Round 26
// 196.776 us; speedup vs baseline: 1.0139x; 1.0139x over previous
//
#include <hip/hip_runtime.h>

typedef unsigned short u16;
typedef short s16x8 __attribute__((ext_vector_type(8)));
typedef float f32x4 __attribute__((ext_vector_type(4)));
typedef float f32x16 __attribute__((ext_vector_type(16)));

__device__ __forceinline__ u16 f2bf(float f) {
  union { float f; unsigned u; } x; x.f = f;
  unsigned r = (x.u + 0x7fffu + ((x.u >> 16) & 1u)) >> 16;
  return (u16)r;
}
__device__ __forceinline__ unsigned bfbits_t(float f) {   // truncating, as u32 low bits
  union { float f; unsigned u; } x; x.f = f;
  return x.u >> 16;
}
__device__ __forceinline__ float bf2f(u16 u) {
  union { unsigned u; float f; } x; x.u = ((unsigned)u) << 16;
  return x.f;
}

__device__ __forceinline__ void load_lds16(const u16* g, void* lds) {
  __builtin_amdgcn_global_load_lds(
      (const __attribute__((address_space(1))) unsigned int*)g,
      (__attribute__((address_space(3))) unsigned int*)lds, 16, 0, 0);
}

// ---------------- fused prep kernel ----------------
__global__ __launch_bounds__(256) void prep_kernel(
    const float* __restrict__ x,
    const float* __restrict__ wq, const float* __restrict__ wk,
    const float* __restrict__ wv,
    const float* __restrict__ bq, const float* __restrict__ bk,
    const float* __restrict__ bv,
    const float* __restrict__ wo,
    u16* __restrict__ xb, u16* __restrict__ wqkv,
    float* __restrict__ bqkv, u16* __restrict__ wob,
    float* __restrict__ cosb, float* __restrict__ sinb) {
  const int R0 = 2097152;            // x: 4096*2048/4
  const int R1 = R0 + 1572864;       // wqkv: 3072*2048/4
  const int R2 = R1 + 1048576;       // wo: 2048*2048/4
  const int R3 = R2 + 768;           // bias: 3072/4
  const int R4 = R3 + 131072;        // rope table: 2048*64
  for (int id = blockIdx.x * 256 + threadIdx.x; id < R4; id += gridDim.x * 256) {
    if (id < R0) {
      float4 v = ((const float4*)x)[id];
      u16* d = xb + (size_t)id * 4;
      d[0] = f2bf(v.x); d[1] = f2bf(v.y); d[2] = f2bf(v.z); d[3] = f2bf(v.w);
    } else if (id < R1) {
      int g = id - R0;
      int row = g >> 9, c4 = (g & 511) * 4;
      const float* src; int srow;
      if (row < 2048)      { src = wq; srow = row; }
      else if (row < 2560) { src = wk; srow = row - 2048; }
      else                 { src = wv; srow = row - 2560; }
      float4 v = *(const float4*)&src[(size_t)srow * 2048 + c4];
      u16* d = wqkv + (size_t)row * 2048 + c4;
      d[0] = f2bf(v.x); d[1] = f2bf(v.y); d[2] = f2bf(v.z); d[3] = f2bf(v.w);
    } else if (id < R2) {
      int g = id - R1;
      float4 v = ((const float4*)wo)[g];
      u16* d = wob + (size_t)g * 4;
      d[0] = f2bf(v.x); d[1] = f2bf(v.y); d[2] = f2bf(v.z); d[3] = f2bf(v.w);
    } else if (id < R3) {
      int g4 = (id - R2) * 4;        // boundaries 2048/2560 are 4-aligned
      float4 v;
      if (g4 < 2048)      v = *(const float4*)&bq[g4];
      else if (g4 < 2560) v = *(const float4*)&bk[g4 - 2048];
      else                v = *(const float4*)&bv[g4 - 2560];
      *(float4*)&bqkv[g4] = v;
    } else {
      int g = id - R3;
      int s = g >> 6, i = g & 63;
      float freq = powf(10000.0f, -(float)i / 64.0f);
      float ang = (float)s * freq;
      cosb[g] = cosf(ang);
      sinb[g] = sinf(ang);
    }
  }
}

// in-place RoPE on Qb (32*2048 rows) and Kbuf (8*2048 rows), fused
__global__ __launch_bounds__(256) void rope_all_kernel(u16* __restrict__ Qb,
                                                       u16* __restrict__ Kbuf,
                                                       const float* __restrict__ cosb,
                                                       const float* __restrict__ sinb) {
  const int total = (32 + 8) * 2048 * 64;   // 5,242,880
  for (int id = blockIdx.x * 256 + threadIdx.x; id < total; id += gridDim.x * 256) {
    int i = id & 63;
    int rs = id >> 6;
    int s = rs & 2047;
    u16* p;
    size_t base;
    if (rs < 65536) { p = Qb;   base = (size_t)rs * 128; }
    else            { p = Kbuf; base = (size_t)(rs - 65536) * 128; }
    float x1 = bf2f(p[base + i]);
    float x2 = bf2f(p[base + i + 64]);
    float c = cosb[s * 64 + i], sn = sinb[s * 64 + i];
    p[base + i]      = f2bf(x1 * c - x2 * sn);
    p[base + i + 64] = f2bf(x2 * c + x1 * sn);
  }
}

// V [8][2048][128] -> Vt [8][128][2048]
__global__ __launch_bounds__(256) void transpose_v_kernel(const u16* __restrict__ V,
                                                          u16* __restrict__ Vt) {
  __shared__ u16 tile[64][130];
  const int t = threadIdx.x;
  const int hb = blockIdx.x, s0 = blockIdx.y * 64;
  const u16* src = V + ((size_t)hb * 2048 + s0) * 128;
#pragma unroll
  for (int i = 0; i < 4; ++i) {
    int c = i * 256 + t;            // 0..1023
    int s = c >> 4, d8 = (c & 15) * 8;
    *(s16x8*)&tile[s][d8] = *(const s16x8*)&src[(size_t)s * 128 + d8];
  }
  __syncthreads();
  u16* dst = Vt + (size_t)hb * 128 * 2048 + s0;
#pragma unroll
  for (int i = 0; i < 4; ++i) {
    int c = i * 256 + t;
    int d = c & 127, s8 = (c >> 7) * 8;
    s16x8 v;
#pragma unroll
    for (int e = 0; e < 8; ++e) v[e] = (short)tile[s8 + e][d];
    *(s16x8*)&dst[(size_t)d * 2048 + s8] = v;
  }
}

// ---------------- bf16 MFMA GEMM v3: 8-wave 128x128, BK=64 (r16/r22, verified) ----
// Schedule space fully mapped: BK{32,64} x tile{128^2,256x128} x waves{4,8} x
// sync{__syncthreads, 1-barrier, counted-vmcnt} x epilogue{row-major, fused-Vt}
// -> this config is the optimum (r13/r17/r21/r23/r25 regressions documented).
__global__ __launch_bounds__(512) void gemm_bt_kernel(
    const u16* __restrict__ A, const u16* __restrict__ Bw,
    const float* __restrict__ bias,
    float* __restrict__ C, int ldc,
    u16* __restrict__ Qp, u16* __restrict__ Kp, u16* __restrict__ Vp,
    int M, int N, int K, int mode) {
  __shared__ u16 sA[128 * 64];   // 16 KB
  __shared__ u16 sB[128 * 64];   // 16 KB
  const int t = threadIdx.x;     // 0..511
  const int w = t >> 6, l = t & 63;
  const int lg = l >> 4, lr = l & 15;
  const int wm = (w >> 2) * 64, wn = (w & 3) * 32;
  const int m0 = blockIdx.y * 128, n0 = blockIdx.x * 128;

  f32x4 acc[4][2];
#pragma unroll
  for (int i = 0; i < 4; ++i)
#pragma unroll
    for (int j = 0; j < 2; ++j)
#pragma unroll
      for (int r = 0; r < 4; ++r) acc[i][j][r] = 0.0f;

  for (int k0 = 0; k0 < K; k0 += 64) {
#pragma unroll
    for (int i = 0; i < 2; ++i) {
      int c = i * 512 + t;
      int row = c >> 3, cc = (c & 7) ^ (row & 7);
      load_lds16(A + (size_t)(m0 + row) * K + k0 + cc * 8,
                 (char*)sA + i * 8192 + w * 1024);
      load_lds16(Bw + (size_t)(n0 + row) * K + k0 + cc * 8,
                 (char*)sB + i * 8192 + w * 1024);
    }
    __syncthreads();
#pragma unroll
    for (int kc = 0; kc < 2; ++kc) {
      const int rch = (((kc * 4 + lg) ^ (lr & 7)) * 8);
      s16x8 af[4], bf[2];
#pragma unroll
      for (int m = 0; m < 4; ++m)
        af[m] = *(const s16x8*)&sA[(wm + m * 16 + lr) * 64 + rch];
#pragma unroll
      for (int n = 0; n < 2; ++n)
        bf[n] = *(const s16x8*)&sB[(wn + n * 16 + lr) * 64 + rch];
#pragma unroll
      for (int m = 0; m < 4; ++m)
#pragma unroll
        for (int n = 0; n < 2; ++n)
          acc[m][n] = __builtin_amdgcn_mfma_f32_16x16x32_bf16(af[m], bf[n], acc[m][n], 0, 0, 0);
    }
    __syncthreads();
  }

#pragma unroll
  for (int m = 0; m < 4; ++m) {
#pragma unroll
    for (int n = 0; n < 2; ++n) {
#pragma unroll
      for (int r = 0; r < 4; ++r) {
        int row = m0 + wm + m * 16 + (lg << 2) + r;
        int col = n0 + wn + n * 16 + lr;
        float val = acc[m][n][r];
        if (mode == 0) {
          val += bias[col];
          int b = row >> 11, s = row & 2047;
          u16 bvv = f2bf(val);
          if (col < 2048) {
            int h = col >> 7, d = col & 127;
            Qp[(((size_t)(b * 16 + h)) * 2048 + s) * 128 + d] = bvv;
          } else if (col < 2560) {
            int cc = col - 2048; int kh = cc >> 7, d = cc & 127;
            Kp[(((size_t)(b * 4 + kh)) * 2048 + s) * 128 + d] = bvv;
          } else {
            int cc = col - 2560; int kh = cc >> 7, d = cc & 127;
            Vp[(((size_t)(b * 4 + kh)) * 2048 + s) * 128 + d] = bvv;
          }
        } else {
          C[(size_t)row * ldc + col] = val;
        }
      }
    }
  }
}

// ---------------- flash v14: KVB=128, 16-chunk 2-way-free swizzle (verified) -------
__device__ const int PH_QC[16] = {7,-1, 7,0, 6,-1, 6,1, 5,-1, 5,2, 4,-1, 4,3};
__device__ const int PH_J0[16] = {0,0, 9,0, 0,0, 9,0, 0,0, 9,0, 0,0, 9,0};
__device__ const int PH_NT[16] = {9,0, 7,2, 9,0, 5,4, 9,0, 3,6, 9,0, 1,8};
__device__ const int PH_MD[16] = {1,0, 2,0, 1,0, 2,0, 1,0, 2,0, 1,0, 2,0};

__global__ __launch_bounds__(512) void flash_mfma_kernel(const u16* __restrict__ Q,
                                                         const u16* __restrict__ Kb,
                                                         const u16* __restrict__ Vtb,
                                                         u16* __restrict__ O,
                                                         u16* __restrict__ po,
                                                         float* __restrict__ pml) {
  const int S = 2048;
  __shared__ u16 sK[128 * 128];      // [j][d], chunk XOR (j&15), single buffer
  __shared__ u16 sVt[2 * 128 * 128]; // [buf][d][j], chunk XOR (d&15)

  const int t = threadIdx.x, w = t >> 6, l = t & 63;
  const int l31 = l & 31, hi = l >> 5;
  const int bh = blockIdx.x, b = bh >> 4, h = bh & 15, kvh = h >> 2;
  const int slot = blockIdx.y;

  const u16* kbase = Kb + ((size_t)(b * 4 + kvh)) * S * 128;
  const u16* vtbase = Vtb + ((size_t)(b * 4 + kvh)) * 128 * S;

  const float C2 = 0.12753785f;   // (1/sqrt(128)) * log2(e)

  auto stageK = [&](int kt) {
#pragma unroll
    for (int i = 0; i < 4; ++i) {
      int c = i * 512 + t;
      int j = c >> 4, cc = (c & 15) ^ (j & 15);
      load_lds16(kbase + ((size_t)(kt * 128 + j) * 128 + cc * 8),
                 (char*)sK + (i * 8192 + w * 1024));
    }
  };
  auto stageV = [&](int kt, int buf) {
#pragma unroll
    for (int i = 0; i < 4; ++i) {
      int c = i * 512 + t;
      int d = c >> 4, cc = (c & 15) ^ (d & 15);
      load_lds16(vtbase + ((size_t)d * S + kt * 128 + cc * 8),
                 (char*)sVt + buf * 32768 + (i * 8192 + w * 1024));
    }
  };

#pragma unroll 1
  for (int ph = 0; ph < 2; ++ph) {
    const int qc = PH_QC[slot * 2 + ph];
    const int ntc = PH_NT[slot * 2 + ph];
    if (ntc == 0) break;
    const int j0 = PH_J0[slot * 2 + ph];
    const int md = PH_MD[slot * 2 + ph];
    const int qw = qc * 256 + w * 32;
    const int q_glob = qw + l31;

    // Q (B-operand) in regs: qb[ks][e] = Q[qw + l31][ks*16 + hi*8 + e]
    const u16* qbase = Q + ((size_t)bh * S + qw) * 128;
    s16x8 qb[8];
#pragma unroll
    for (int ks = 0; ks < 8; ++ks)
      qb[ks] = *(const s16x8*)&qbase[(size_t)l31 * 128 + ks * 16 + hi * 8];

    f32x16 o0, o1, o2, o3;
#pragma unroll
    for (int r = 0; r < 16; ++r) { o0[r] = 0.f; o1[r] = 0.f; o2[r] = 0.f; o3[r] = 0.f; }
    float mrun = -3e38f, lsum = 0.0f;

    stageV(j0, 0);
    stageK(j0);
    __syncthreads();   // drain -> K[j0], V[j0] ready

    int cur = 0;
    for (int kt2 = 0; kt2 < ntc; ++kt2) {
      const int kt = j0 + kt2;
      const bool act = (kt * 128 <= qw + 31);
      const bool more = (kt2 + 1 < ntc);

      if (more) stageV(kt + 1, cur ^ 1);   // V[cur^1] free since PV(kt-1)

      f32x16 sc0, sc1, sc2, sc3;
      if (act) {
        // ---- QK^T swapped: sc = mfma32(K, Q), 32 MFMA over 4 j-blocks ----
#pragma unroll
        for (int r = 0; r < 16; ++r) { sc0[r] = 0.f; sc1[r] = 0.f; sc2[r] = 0.f; sc3[r] = 0.f; }
        const int chkb = (l31 & 15);
        __builtin_amdgcn_s_setprio(1);
#pragma unroll
        for (int ks = 0; ks < 8; ++ks) {
          int chk = ((2 * ks + hi) ^ chkb) * 8;
          s16x8 kf0 = *(const s16x8*)&sK[(l31) * 128 + chk];
          s16x8 kf1 = *(const s16x8*)&sK[(32 + l31) * 128 + chk];
          s16x8 kf2 = *(const s16x8*)&sK[(64 + l31) * 128 + chk];
          s16x8 kf3 = *(const s16x8*)&sK[(96 + l31) * 128 + chk];
          sc0 = __builtin_amdgcn_mfma_f32_32x32x16_bf16(kf0, qb[ks], sc0, 0, 0, 0);
          sc1 = __builtin_amdgcn_mfma_f32_32x32x16_bf16(kf1, qb[ks], sc1, 0, 0, 0);
          sc2 = __builtin_amdgcn_mfma_f32_32x32x16_bf16(kf2, qb[ks], sc2, 0, 0, 0);
          sc3 = __builtin_amdgcn_mfma_f32_32x32x16_bf16(kf3, qb[ks], sc3, 0, 0, 0);
        }
        __builtin_amdgcn_s_setprio(0);
      }

      __syncthreads();   // barrier A: QK reads of sK done (drains V[kt+1] too)

      if (more) stageK(kt + 1);

      if (act) {
        const u16* sVc = &sVt[cur * 16384];

        // ---- causal mask (diagonal tiles only) ----
        if (kt * 128 + 127 > qw) {
          const int j0m = kt * 128;
#pragma unroll
          for (int r = 0; r < 16; ++r) {
            int jr = j0m + (r & 3) + 8 * (r >> 2) + 4 * hi;
            sc0[r] = (jr <= q_glob) ? sc0[r] : -3e38f;
            sc1[r] = (jr + 32 <= q_glob) ? sc1[r] : -3e38f;
            sc2[r] = (jr + 64 <= q_glob) ? sc2[r] : -3e38f;
            sc3[r] = (jr + 96 <= q_glob) ? sc3[r] : -3e38f;
          }
        }

        // ---- online softmax over full tile (defer-max THR=8) ----
        float tm[16];
#pragma unroll
        for (int r = 0; r < 16; ++r)
          tm[r] = fmaxf(fmaxf(sc0[r], sc1[r]), fmaxf(sc2[r], sc3[r]));
#pragma unroll
        for (int s2 = 8; s2 >= 1; s2 >>= 1)
#pragma unroll
          for (int r = 0; r < s2; ++r) tm[r] = fmaxf(tm[r], tm[r + s2]);
        float mt = fmaxf(tm[0], __shfl_xor(tm[0], 32));
        float mt2 = mt * C2;
        bool resc = (mt2 > mrun + 8.0f);
        if (resc) {
          float Mn = mt2;
          float corr = exp2f(mrun - Mn);
          lsum *= corr;
#pragma unroll
          for (int r = 0; r < 16; ++r) {
            o0[r] *= corr; o1[r] *= corr; o2[r] *= corr; o3[r] *= corr;
          }
          mrun = Mn;
        }
        const float Mn = mrun;
        float lacc = 0.0f;

        // ---- half 0: P from sc0/sc1 (j 0..63), PV with V chunks 0..7 ----
        {
          unsigned pk[16];
#pragma unroll
          for (int m = 0; m < 8; ++m) {
            float pa_ = exp2f(__builtin_fmaf(sc0[2 * m], C2, -Mn));
            float pb_ = exp2f(__builtin_fmaf(sc0[2 * m + 1], C2, -Mn));
            lacc += pa_ + pb_;
            pk[m] = (bfbits_t(pb_) << 16) | bfbits_t(pa_);
          }
#pragma unroll
          for (int m = 0; m < 8; ++m) {
            float pa_ = exp2f(__builtin_fmaf(sc1[2 * m], C2, -Mn));
            float pb_ = exp2f(__builtin_fmaf(sc1[2 * m + 1], C2, -Mn));
            lacc += pa_ + pb_;
            pk[8 + m] = (bfbits_t(pb_) << 16) | bfbits_t(pa_);
          }
          unsigned pkx[16];
#pragma unroll
          for (int i = 0; i < 16; ++i) pkx[i] = __shfl_xor(pk[i], 32);
          __builtin_amdgcn_s_setprio(1);
#pragma unroll
          for (int ks = 0; ks < 4; ++ks) {
            const int base = (ks >> 1) * 8 + 4 * (ks & 1);
            unsigned pw[4];
            pw[0] = hi ? pkx[base + 2] : pk[base + 0];
            pw[1] = hi ? pkx[base + 3] : pk[base + 1];
            pw[2] = hi ? pk[base + 2] : pkx[base + 0];
            pw[3] = hi ? pk[base + 3] : pkx[base + 1];
            s16x8 pa = *(const s16x8*)pw;
#pragma unroll
            for (int dt = 0; dt < 4; ++dt) {
              int d = dt * 32 + l31;
              s16x8 vt = *(const s16x8*)&sVc[d * 128 + (((2 * ks + hi) ^ (d & 15)) * 8)];
              if (dt == 0) o0 = __builtin_amdgcn_mfma_f32_32x32x16_bf16(vt, pa, o0, 0, 0, 0);
              if (dt == 1) o1 = __builtin_amdgcn_mfma_f32_32x32x16_bf16(vt, pa, o1, 0, 0, 0);
              if (dt == 2) o2 = __builtin_amdgcn_mfma_f32_32x32x16_bf16(vt, pa, o2, 0, 0, 0);
              if (dt == 3) o3 = __builtin_amdgcn_mfma_f32_32x32x16_bf16(vt, pa, o3, 0, 0, 0);
            }
          }
          __builtin_amdgcn_s_setprio(0);
        }

        // ---- half 1: P from sc2/sc3 (j 64..127), PV with V chunks 8..15 ----
        {
          unsigned pk[16];
#pragma unroll
          for (int m = 0; m < 8; ++m) {
            float pa_ = exp2f(__builtin_fmaf(sc2[2 * m], C2, -Mn));
            float pb_ = exp2f(__builtin_fmaf(sc2[2 * m + 1], C2, -Mn));
            lacc += pa_ + pb_;
            pk[m] = (bfbits_t(pb_) << 16) | bfbits_t(pa_);
          }
#pragma unroll
          for (int m = 0; m < 8; ++m) {
            float pa_ = exp2f(__builtin_fmaf(sc3[2 * m], C2, -Mn));
            float pb_ = exp2f(__builtin_fmaf(sc3[2 * m + 1], C2, -Mn));
            lacc += pa_ + pb_;
            pk[8 + m] = (bfbits_t(pb_) << 16) | bfbits_t(pa_);
          }
          unsigned pkx[16];
#pragma unroll
          for (int i = 0; i < 16; ++i) pkx[i] = __shfl_xor(pk[i], 32);
          __builtin_amdgcn_s_setprio(1);
#pragma unroll
          for (int ks = 0; ks < 4; ++ks) {
            const int base = (ks >> 1) * 8 + 4 * (ks & 1);
            unsigned pw[4];
            pw[0] = hi ? pkx[base + 2] : pk[base + 0];
            pw[1] = hi ? pkx[base + 3] : pk[base + 1];
            pw[2] = hi ? pk[base + 2] : pkx[base + 0];
            pw[3] = hi ? pk[base + 3] : pkx[base + 1];
            s16x8 pa = *(const s16x8*)pw;
#pragma unroll
            for (int dt = 0; dt < 4; ++dt) {
              int d = dt * 32 + l31;
              s16x8 vt = *(const s16x8*)&sVc[d * 128 + (((8 + 2 * ks + hi) ^ (d & 15)) * 8)];
              if (dt == 0) o0 = __builtin_amdgcn_mfma_f32_32x32x16_bf16(vt, pa, o0, 0, 0, 0);
              if (dt == 1) o1 = __builtin_amdgcn_mfma_f32_32x32x16_bf16(vt, pa, o1, 0, 0, 0);
              if (dt == 2) o2 = __builtin_amdgcn_mfma_f32_32x32x16_bf16(vt, pa, o2, 0, 0, 0);
              if (dt == 3) o3 = __builtin_amdgcn_mfma_f32_32x32x16_bf16(vt, pa, o3, 0, 0, 0);
            }
          }
          __builtin_amdgcn_s_setprio(0);
        }
        lsum += lacc;
      }

      __syncthreads();   // barrier B: drains K[kt+1]; protects sK reuse
      cur ^= 1;
    }

    // ---- epilogue: denominator reduce, normalize, store (full or partial) ----
    float ls = lsum + __shfl_xor(lsum, 32);
    float inv = (ls > 0.0f) ? 1.0f / ls : 0.0f;
    if (md == 0) {
      size_t obase = ((size_t)b * S + q_glob) * 2048 + h * 128;
#pragma unroll
      for (int dt = 0; dt < 4; ++dt) {
        const f32x16& ov = (dt == 0) ? o0 : (dt == 1) ? o1 : (dt == 2) ? o2 : o3;
#pragma unroll
        for (int g = 0; g < 4; ++g) {
          int d0 = dt * 32 + 8 * g + 4 * hi;
          unsigned u0 = (unsigned)f2bf(ov[4 * g] * inv) | ((unsigned)f2bf(ov[4 * g + 1] * inv) << 16);
          unsigned u1 = (unsigned)f2bf(ov[4 * g + 2] * inv) | ((unsigned)f2bf(ov[4 * g + 3] * inv) << 16);
          uint2 u; u.x = u0; u.y = u1;
          *(uint2*)&O[obase + d0] = u;
        }
      }
    } else {
      const int pid = ((bh << 2) + (qc - 4)) * 2 + (md - 1);
      const int qrow = w * 32 + l31;
      size_t pbase = (size_t)pid * 32768 + (size_t)qrow * 128;
#pragma unroll
      for (int dt = 0; dt < 4; ++dt) {
        const f32x16& ov = (dt == 0) ? o0 : (dt == 1) ? o1 : (dt == 2) ? o2 : o3;
#pragma unroll
        for (int g = 0; g < 4; ++g) {
          int d0 = dt * 32 + 8 * g + 4 * hi;
          unsigned u0 = (unsigned)f2bf(ov[4 * g] * inv) | ((unsigned)f2bf(ov[4 * g + 1] * inv) << 16);
          unsigned u1 = (unsigned)f2bf(ov[4 * g + 2] * inv) | ((unsigned)f2bf(ov[4 * g + 3] * inv) << 16);
          uint2 u; u.x = u0; u.y = u1;
          *(uint2*)&po[pbase + d0] = u;
        }
      }
      if (hi == 0) {
        pml[pid * 512 + qrow * 2]     = mrun;
        pml[pid * 512 + qrow * 2 + 1] = ls;
      }
    }
    if (ph == 0 && PH_NT[slot * 2 + 1] != 0) __syncthreads();
  }
}

// merge the two halves of each split q-tile: O = w0*o0 + w1*o1, wi = li*2^(mi-M).
__global__ __launch_bounds__(256) void flash_merge_kernel(const u16* __restrict__ po,
                                                          const float* __restrict__ pml,
                                                          u16* __restrict__ att) {
  const int t = threadIdx.x;
  const int tl = blockIdx.x >> 4;            // 0..127
  const int row = (blockIdx.x & 15) * 16 + (t >> 4);
  const int d8 = (t & 15) * 8;
  const int hh2 = tl >> 2, qc = (tl & 3) + 4;
  const int pid0 = tl * 2, pid1 = pid0 + 1;
  float m0 = pml[pid0 * 512 + row * 2], l0 = pml[pid0 * 512 + row * 2 + 1];
  float m1 = pml[pid1 * 512 + row * 2], l1 = pml[pid1 * 512 + row * 2 + 1];
  float M = fmaxf(m0, m1);
  float w0 = l0 * exp2f(m0 - M), w1 = l1 * exp2f(m1 - M);
  float inv = 1.0f / (w0 + w1);
  w0 *= inv; w1 *= inv;
  s16x8 a = *(const s16x8*)&po[(size_t)pid0 * 32768 + row * 128 + d8];
  s16x8 c = *(const s16x8*)&po[(size_t)pid1 * 32768 + row * 128 + d8];
  int b = hh2 >> 4, hh = hh2 & 15;
  size_t base = ((size_t)b * 2048 + qc * 256 + row) * 2048 + hh * 128 + d8;
  u16 outv[8];
#pragma unroll
  for (int e = 0; e < 8; ++e)
    outv[e] = f2bf(w0 * bf2f((u16)a[e]) + w1 * bf2f((u16)c[e]));
  *(s16x8*)&att[base] = *(const s16x8*)outv;
}

// ---------------- launch ----------------

extern "C" void kernel_launch(void* const* d_in, const int* in_sizes, int n_in,
                              void* d_out, int out_size, void* d_ws, size_t ws_size,
                              hipStream_t stream) {
  const float* x  = (const float*)d_in[0];
  const float* wq = (const float*)d_in[1];
  const float* bq = (const float*)d_in[2];
  const float* wk = (const float*)d_in[3];
  const float* bk = (const float*)d_in[4];
  const float* wv = (const float*)d_in[5];
  const float* bv = (const float*)d_in[6];
  const float* wo = (const float*)d_in[7];
  float* out = (float*)d_out;

  char* ws = (char*)d_ws;
  u16* xb    = (u16*)ws;    ws += (size_t)4096 * 2048 * 2;
  u16* wqkv  = (u16*)ws;    ws += (size_t)3072 * 2048 * 2;
  float* bqkv = (float*)ws; ws += (size_t)3072 * 4;
  u16* wob   = (u16*)ws;    ws += (size_t)2048 * 2048 * 2;
  u16* Qb    = (u16*)ws;    ws += (size_t)32 * 2048 * 128 * 2;
  u16* Kbuf  = (u16*)ws;    ws += (size_t)8 * 2048 * 128 * 2;
  u16* Vbuf  = (u16*)ws;    ws += (size_t)8 * 2048 * 128 * 2;
  u16* Vt    = (u16*)ws;    ws += (size_t)8 * 128 * 2048 * 2;
  float* cosb = (float*)ws; ws += (size_t)2048 * 64 * 4;
  float* sinb = (float*)ws; ws += (size_t)2048 * 64 * 4;
  u16* att   = (u16*)ws;    ws += (size_t)4096 * 2048 * 2;

  // partial buffers ALIAS dead regions (stream-ordered, safe):
  u16* po = xb;              // 256 partials x 64 KB = 16.78 MB = xb exactly; xb dead after qkv GEMM
  float* pml = (float*)Vbuf; // 256 x 512 floats = 524 KB; Vbuf dead after transpose_v

  prep_kernel<<<2048, 256, 0, stream>>>(x, wq, wk, wv, bq, bk, bv, wo,
                                        xb, wqkv, bqkv, wob, cosb, sinb);

  gemm_bt_kernel<<<dim3(24, 32), 512, 0, stream>>>(xb, wqkv, bqkv, nullptr, 0,
                                                   Qb, Kbuf, Vbuf, 4096, 3072, 2048, 0);
  transpose_v_kernel<<<dim3(8, 32), 256, 0, stream>>>(Vbuf, Vt);
  rope_all_kernel<<<2048, 256, 0, stream>>>(Qb, Kbuf, cosb, sinb);

  flash_mfma_kernel<<<dim3(32, 8), 512, 0, stream>>>(Qb, Kbuf, Vt, att, po, pml);
  flash_merge_kernel<<<2048, 256, 0, stream>>>(po, pml, att);

  gemm_bt_kernel<<<dim3(16, 32), 512, 0, stream>>>(att, wob, nullptr, out, 2048,
                                                   nullptr, nullptr, nullptr, 4096, 2048, 2048, 1);
}